// Round 1
// baseline (266.948 us; speedup 1.0000x reference)
//
#include <hip/hip_runtime.h>

#define FM_BATCH      16384
#define FM_NUM_DENSE  13
#define FM_NUM_FIELDS 26
#define FM_FIELD_SIZE 100000
#define FM_K          32
#define FM_FEAT_LEN   2600013   // 26*100000 + 13

// One sample per 32-lane group (lane = latent dim k).
// accL/accS in registers; 26-field gather fully unrolled for ILP.
__global__ __launch_bounds__(256) void FM_79070347919991_kernel(
    const float* __restrict__ dense,   // [BATCH][13]
    const int*   __restrict__ sparse,  // [BATCH][26] (int32)
    const float* __restrict__ w0,      // [1]
    const float* __restrict__ w,       // [FEAT_LEN]
    const float* __restrict__ V,       // [K][FEAT_LEN]
    float* __restrict__ out)           // [BATCH]
{
    const int tid = blockIdx.x * blockDim.x + threadIdx.x;
    const int b = tid >> 5;   // sample index
    const int k = tid & 31;   // latent dim
    if (b >= FM_BATCH) return;

    const float* __restrict__ db = dense + b * FM_NUM_DENSE;
    const int*   __restrict__ sb = sparse + b * FM_NUM_FIELDS;
    const float* __restrict__ Vk = V + (size_t)k * FM_FEAT_LEN;

    // ---- dense part (redundant across the 32 lanes of a sample; cache-hot) ----
    float accL = 0.f;   // sum_j x_j * V[k,j]
    float accS = 0.f;   // sum_j x_j^2 * V[k,j]^2
    float first = 0.f;  // w0 + sum_j x_j * w_j   (built up below)
    #pragma unroll
    for (int d = 0; d < FM_NUM_DENSE; ++d) {
        const float x = db[d];
        const float v = Vk[d];
        accL  += x * v;
        accS  += (x * x) * (v * v);
        first += x * w[d];
    }

    // ---- sparse part: 26 scattered gathers, fully unrolled so loads pipeline ----
    #pragma unroll
    for (int f = 0; f < FM_NUM_FIELDS; ++f) {
        const int idx = FM_NUM_DENSE + f * FM_FIELD_SIZE + sb[f];
        const float v = Vk[idx];
        accL  += v;
        accS  += v * v;
        first += w[idx];   // same addr across the sample's 32 lanes -> 1 line
    }

    // ---- second-order term: reduce (accL^2 - accS) over k=0..31 ----
    float t = accL * accL - accS;
    #pragma unroll
    for (int m = 16; m >= 1; m >>= 1)
        t += __shfl_xor(t, m);   // masks <32 stay within each 32-lane group

    const float z = first + w0[0] + 0.5f * t;
    if (k == 0)
        out[b] = 1.f / (1.f + __expf(-z));
}

extern "C" void kernel_launch(void* const* d_in, const int* in_sizes, int n_in,
                              void* d_out, int out_size, void* d_ws, size_t ws_size,
                              hipStream_t stream) {
    const float* dense  = (const float*)d_in[0];
    const int*   sparse = (const int*)d_in[1];
    const float* w0     = (const float*)d_in[2];
    const float* w      = (const float*)d_in[3];
    const float* V      = (const float*)d_in[4];
    float* out = (float*)d_out;

    const int threads = FM_BATCH * FM_K;          // 524288
    const int block = 256;
    const int grid = threads / block;             // 2048
    FM_79070347919991_kernel<<<grid, block, 0, stream>>>(dense, sparse, w0, w, V, out);
}

// Round 2
// 266.786 us; speedup vs baseline: 1.0006x; 1.0006x over previous
//
#include <hip/hip_runtime.h>

#define FM_BATCH      16384
#define FM_NUM_DENSE  13
#define FM_NUM_FIELDS 26
#define FM_FIELD_SIZE 100000
#define FM_K          32
#define FM_FEAT_LEN   2600013   // 26*100000 + 13

// One sample per 32-lane group (lane = latent dim k).
// Field loop deliberately NOT unrolled: keeps only ~1-2 fields' scattered
// loads in flight per wave, so the grid walks fields in phase and the
// per-field 12.8 MB V-slice stays LLC-resident (each HBM line fetched once).
__global__ __launch_bounds__(256) void FM_79070347919991_kernel(
    const float* __restrict__ dense,   // [BATCH][13]
    const int*   __restrict__ sparse,  // [BATCH][26] (int32)
    const float* __restrict__ w0,      // [1]
    const float* __restrict__ w,       // [FEAT_LEN]
    const float* __restrict__ V,       // [K][FEAT_LEN]
    float* __restrict__ out)           // [BATCH]
{
    const int tid = blockIdx.x * blockDim.x + threadIdx.x;
    const int b = tid >> 5;   // sample index
    const int k = tid & 31;   // latent dim
    if (b >= FM_BATCH) return;

    const float* __restrict__ db = dense + b * FM_NUM_DENSE;
    const int*   __restrict__ sb = sparse + b * FM_NUM_FIELDS;
    const float* __restrict__ Vk = V + (size_t)k * FM_FEAT_LEN;

    // ---- dense part (redundant across the 32 lanes of a sample; cache-hot) ----
    float accL = 0.f;   // sum_j x_j * V[k,j]
    float accS = 0.f;   // sum_j x_j^2 * V[k,j]^2
    float first = 0.f;  // sum_j x_j * w_j
    #pragma unroll
    for (int d = 0; d < FM_NUM_DENSE; ++d) {
        const float x = db[d];
        const float v = Vk[d];
        accL  += x * v;
        accS  += (x * x) * (v * v);
        first += x * w[d];
    }

    // ---- sparse part: serialized field walk (see comment above) ----
    #pragma unroll 1
    for (int f = 0; f < FM_NUM_FIELDS; ++f) {
        const int idx = FM_NUM_DENSE + f * FM_FIELD_SIZE + sb[f];
        const float v = Vk[idx];
        accL  += v;
        accS  += v * v;
        first += w[idx];   // same addr across the sample's 32 lanes -> 1 line
    }

    // ---- second-order term: reduce (accL^2 - accS) over k=0..31 ----
    float t = accL * accL - accS;
    #pragma unroll
    for (int m = 16; m >= 1; m >>= 1)
        t += __shfl_xor(t, m);   // masks <32 stay within each 32-lane group

    const float z = first + w0[0] + 0.5f * t;
    if (k == 0)
        out[b] = 1.f / (1.f + __expf(-z));
}

extern "C" void kernel_launch(void* const* d_in, const int* in_sizes, int n_in,
                              void* d_out, int out_size, void* d_ws, size_t ws_size,
                              hipStream_t stream) {
    const float* dense  = (const float*)d_in[0];
    const int*   sparse = (const int*)d_in[1];
    const float* w0     = (const float*)d_in[2];
    const float* w      = (const float*)d_in[3];
    const float* V      = (const float*)d_in[4];
    float* out = (float*)d_out;

    const int threads = FM_BATCH * FM_K;          // 524288
    const int block = 256;
    const int grid = threads / block;             // 2048
    FM_79070347919991_kernel<<<grid, block, 0, stream>>>(dense, sparse, w0, w, V, out);
}

// Round 3
// 224.860 us; speedup vs baseline: 1.1872x; 1.1865x over previous
//
#include <hip/hip_runtime.h>

#define FM_BATCH      16384
#define FM_NUM_DENSE  13
#define FM_NUM_FIELDS 26
#define FM_FIELD_SIZE 100000
#define FM_K          32
#define FM_FEAT_LEN   2600013   // 26*100000 + 13
#define FM_KG         8         // k-groups == XCDs
#define FM_KPG        4         // k-rows per group (32/8)
#define FM_SPB        64        // samples per block (256 threads = 64 samples x 4 k)

// Pass 1: per-(sample, k) accumulate accL/accS over dense + 26 sparse fields.
// k is partitioned across XCDs via kg = blockIdx % 8 (round-robin dispatch),
// so each 64B line of V is fetched by exactly ONE XCD's L2, and the per-XCD
// per-field V-slice (4 rows x ~370KB = 1.5MB) stays L2-resident for reuse.
__global__ __launch_bounds__(256, 8) void fm_pass1(
    const float* __restrict__ dense,   // [BATCH][13]
    const int*   __restrict__ sparse,  // [BATCH][26]
    const float* __restrict__ V,       // [K][FEAT_LEN]
    float* __restrict__ ws)            // [BATCH][8] partial second-order sums
{
    const int kg    = blockIdx.x & 7;   // aligns with XCD (round-robin dispatch)
    const int chunk = blockIdx.x >> 3;
    const int t  = threadIdx.x;
    const int s  = t >> 2;              // 0..63 sample-in-block
    const int kk = t & 3;               // 0..3 k-in-group
    const int b  = chunk * FM_SPB + s;
    const int k  = kg * FM_KPG + kk;

    const float* __restrict__ Vk = V + (size_t)k * FM_FEAT_LEN;
    const int*   __restrict__ sb = sparse + b * FM_NUM_FIELDS;
    const float* __restrict__ db = dense + b * FM_NUM_DENSE;

    float accL = 0.f, accS = 0.f;
    #pragma unroll
    for (int d = 0; d < FM_NUM_DENSE; ++d) {
        const float x = db[d];
        const float v = Vk[d];
        accL += x * v;
        accS += (x * x) * (v * v);
    }

    // Serialized field walk: keeps the whole XCD in phase on one 1.5MB slice.
    #pragma unroll 1
    for (int f = 0; f < FM_NUM_FIELDS; ++f) {
        const int idx = FM_NUM_DENSE + f * FM_FIELD_SIZE + sb[f];
        const float v = Vk[idx];
        accL += v;
        accS += v * v;
    }

    // second-order partial for this k, summed over the 4 ks of the group
    float tp = accL * accL - accS;
    tp += __shfl_xor(tp, 1);   // lanes s*4+kk: xor 1,2 sums the quad
    tp += __shfl_xor(tp, 2);
    if (kk == 0)
        ws[b * FM_KG + kg] = tp;
}

// Pass 2: combine 8 partials + first-order terms (w gather) + sigmoid.
__global__ __launch_bounds__(256) void fm_pass2(
    const float* __restrict__ dense,
    const int*   __restrict__ sparse,
    const float* __restrict__ w0,
    const float* __restrict__ w,       // [FEAT_LEN]
    const float* __restrict__ ws,      // [BATCH][8]
    float* __restrict__ out)           // [BATCH]
{
    const int b = blockIdx.x * blockDim.x + threadIdx.x;
    if (b >= FM_BATCH) return;

    const float4* wsb = (const float4*)(ws + b * FM_KG);
    const float4 p0 = wsb[0], p1 = wsb[1];
    const float tsum = p0.x + p0.y + p0.z + p0.w + p1.x + p1.y + p1.z + p1.w;

    float first = w0[0];
    const float* __restrict__ db = dense + b * FM_NUM_DENSE;
    #pragma unroll
    for (int d = 0; d < FM_NUM_DENSE; ++d)
        first += db[d] * w[d];

    const int* __restrict__ sb = sparse + b * FM_NUM_FIELDS;
    #pragma unroll
    for (int f = 0; f < FM_NUM_FIELDS; ++f)
        first += w[FM_NUM_DENSE + f * FM_FIELD_SIZE + sb[f]];

    const float z = first + 0.5f * tsum;
    out[b] = 1.f / (1.f + __expf(-z));
}

extern "C" void kernel_launch(void* const* d_in, const int* in_sizes, int n_in,
                              void* d_out, int out_size, void* d_ws, size_t ws_size,
                              hipStream_t stream) {
    const float* dense  = (const float*)d_in[0];
    const int*   sparse = (const int*)d_in[1];
    const float* w0     = (const float*)d_in[2];
    const float* w      = (const float*)d_in[3];
    const float* V      = (const float*)d_in[4];
    float* out = (float*)d_out;
    float* ws  = (float*)d_ws;   // needs BATCH*8*4 = 512 KB

    const int grid1 = (FM_BATCH / FM_SPB) * FM_KG;   // 256 chunks x 8 kg = 2048
    fm_pass1<<<grid1, 256, 0, stream>>>(dense, sparse, V, ws);

    const int grid2 = (FM_BATCH + 255) / 256;        // 64
    fm_pass2<<<grid2, 256, 0, stream>>>(dense, sparse, w0, w, ws, out);
}

// Round 4
// 184.120 us; speedup vs baseline: 1.4499x; 1.2213x over previous
//
#include <hip/hip_runtime.h>

#define FM_BATCH      16384
#define FM_NUM_DENSE  13
#define FM_NUM_FIELDS 26
#define FM_FIELD_SIZE 100000
#define FM_K          32
#define FM_FEAT_LEN   2600013   // 26*100000 + 13
#define FM_SG         8         // sample groups
#define FM_SPG        2048      // samples per group (16384/8)
#define SORT_N        2048

// ws layout (uint32 units):
//   keys: [26][8][2048] u32  = (idx<<11 | local_b), sorted ascending by idx
//   tp:   [16384][32]  f32   second-order partial per (sample, k)
#define WS_TP_OFF (FM_NUM_FIELDS * FM_SG * SORT_N)   // 425984 u32 = 1.7 MB

// ---- Kernel 1: per (field, sample-group) bitonic sort of (idx, b) pairs ----
__global__ __launch_bounds__(256) void fm_sort(
    const int* __restrict__ sparse,      // [BATCH][26]
    unsigned int* __restrict__ keys)
{
    const int f  = blockIdx.x / FM_SG;
    const int sg = blockIdx.x % FM_SG;
    __shared__ unsigned int s[SORT_N];
    for (int i = threadIdx.x; i < SORT_N; i += 256) {
        const int b = sg * FM_SPG + i;
        s[i] = ((unsigned)sparse[b * FM_NUM_FIELDS + f] << 11) | (unsigned)i;
    }
    for (int len = 2; len <= SORT_N; len <<= 1) {
        for (int inc = len >> 1; inc > 0; inc >>= 1) {
            __syncthreads();
            for (int x = threadIdx.x; x < SORT_N; x += 256) {
                const int y = x ^ inc;
                if (y > x) {
                    const unsigned a = s[x], c = s[y];
                    const bool up = ((x & len) == 0);
                    if ((a > c) == up) { s[x] = c; s[y] = a; }
                }
            }
        }
    }
    __syncthreads();
    unsigned int* dst = keys + (f * FM_SG + sg) * SORT_N;
    for (int i = threadIdx.x; i < SORT_N; i += 256) dst[i] = s[i];
}

// ---- Kernel 2: sorted monotone gather; acc in LDS; one owner per (b,k) ----
// bid = sg*32 + k  ->  bid%8 == k%8: all 8 sample-group blocks of a k-row
// land on the same XCD (round-robin dispatch), so the row is fetched once.
__global__ __launch_bounds__(1024) void fm_main(
    const float* __restrict__ dense,     // [BATCH][13]
    const unsigned int* __restrict__ keys,
    const float* __restrict__ V,         // [K][FEAT_LEN]
    float* __restrict__ tp)              // [BATCH][32]
{
    const int k  = blockIdx.x & 31;
    const int sg = blockIdx.x >> 5;
    __shared__ float accL[FM_SPG];
    __shared__ float accS[FM_SPG];
    const float* __restrict__ Vk = V + (size_t)k * FM_FEAT_LEN;

    // dense init (assign, not +=, also clears poisoned LDS)
    for (int i = threadIdx.x; i < FM_SPG; i += 1024) {
        const int b = sg * FM_SPG + i;
        float aL = 0.f, aS = 0.f;
        #pragma unroll
        for (int d = 0; d < FM_NUM_DENSE; ++d) {
            const float x = dense[b * FM_NUM_DENSE + d];
            const float v = Vk[d];
            aL += x * v;
            aS += (x * x) * (v * v);
        }
        accL[i] = aL; accS[i] = aS;
    }
    __syncthreads();

    for (int f = 0; f < FM_NUM_FIELDS; ++f) {
        const unsigned int* kl = keys + (f * FM_SG + sg) * SORT_N;
        const float* __restrict__ Vf = Vk + FM_NUM_DENSE + f * FM_FIELD_SIZE;
        // lb unique within a field's list -> LDS RMW race-free; unroll both
        // strided iterations so the two gathers are in flight together.
        #pragma unroll 2
        for (int i = threadIdx.x; i < FM_SPG; i += 1024) {
            const unsigned key = kl[i];
            const unsigned idx = key >> 11;
            const unsigned lb  = key & 2047u;
            const float v = Vf[idx];
            accL[lb] += v;
            accS[lb] += v * v;
        }
        __syncthreads();   // no same-lb overlap across fields
    }

    for (int i = threadIdx.x; i < FM_SPG; i += 1024) {
        const float t = accL[i] * accL[i] - accS[i];
        tp[(size_t)(sg * FM_SPG + i) * FM_K + k] = t;
    }
}

// ---- Kernel 3: reduce 32 partials + first-order (w gather) + sigmoid ----
__global__ __launch_bounds__(256) void fm_finish(
    const float* __restrict__ dense,
    const int*   __restrict__ sparse,
    const float* __restrict__ w0,
    const float* __restrict__ w,
    const float* __restrict__ tp,
    float* __restrict__ out)
{
    const int b = blockIdx.x * blockDim.x + threadIdx.x;
    if (b >= FM_BATCH) return;
    const float4* t4 = (const float4*)(tp + (size_t)b * FM_K);
    float ts = 0.f;
    #pragma unroll
    for (int i = 0; i < FM_K / 4; ++i) {
        const float4 p = t4[i];
        ts += p.x + p.y + p.z + p.w;
    }
    float first = w0[0];
    #pragma unroll
    for (int d = 0; d < FM_NUM_DENSE; ++d)
        first += dense[b * FM_NUM_DENSE + d] * w[d];
    #pragma unroll
    for (int f = 0; f < FM_NUM_FIELDS; ++f)
        first += w[FM_NUM_DENSE + f * FM_FIELD_SIZE + sparse[b * FM_NUM_FIELDS + f]];
    const float z = first + 0.5f * ts;
    out[b] = 1.f / (1.f + __expf(-z));
}

extern "C" void kernel_launch(void* const* d_in, const int* in_sizes, int n_in,
                              void* d_out, int out_size, void* d_ws, size_t ws_size,
                              hipStream_t stream) {
    const float* dense  = (const float*)d_in[0];
    const int*   sparse = (const int*)d_in[1];
    const float* w0     = (const float*)d_in[2];
    const float* w      = (const float*)d_in[3];
    const float* V      = (const float*)d_in[4];
    float* out = (float*)d_out;

    unsigned int* keys = (unsigned int*)d_ws;                 // 1.7 MB
    float*        tpb  = (float*)d_ws + WS_TP_OFF;            // 2.0 MB

    fm_sort<<<FM_NUM_FIELDS * FM_SG, 256, 0, stream>>>(sparse, keys);
    fm_main<<<FM_K * FM_SG, 1024, 0, stream>>>(dense, keys, V, tpb);
    fm_finish<<<(FM_BATCH + 255) / 256, 256, 0, stream>>>(dense, sparse, w0, w, tpb, out);
}